// Round 1
// baseline (867.784 us; speedup 1.0000x reference)
//
#include <hip/hip_runtime.h>

// VQ quantize: N=65536 tokens, D=256, K=1024 codes.
// Round 1: correctness-first fp32 vector-ALU implementation.
//   - fused distance GEMM + running argmax (2*x.w - |w|^2, xsq drops out of argmax)
//   - fused epilogue: gather quantize from wT (L2-resident), loss partial, dw atomics
//   - dw accumulated as dwT[K][D] (coalesced atomics) then transposed to [D][K]

#define D 256
#define K 1024
#define NTOK 65536
#define MT 64            // tokens per block
#define NT 64            // codes per chunk
#define NCHUNK (K / NT)
#define XSTR 260         // x-tile LDS row stride (pad: keeps float4 align, breaks 4-way bank conflict)

// flat float32 output offsets (return-order concat)
#define OFF_Q   ((size_t)1)
#define OFF_CS  ((size_t)1 + (size_t)NTOK * D)     // 16777217
#define OFF_DW  (OFF_CS + K)                        // 16778241
#define OFF_IDX (OFF_DW + (size_t)D * K)            // 17040385
#define OFF_P   (OFF_IDX + NTOK)                    // 17105921

__global__ __launch_bounds__(256) void transpose_w(const float* __restrict__ w,
                                                   float* __restrict__ wT) {
  __shared__ float tile[32][33];
  const int k0 = blockIdx.x * 32, d0 = blockIdx.y * 32;
  const int tx = threadIdx.x, ty = threadIdx.y;  // 32x8
#pragma unroll
  for (int j = 0; j < 4; ++j) {
    const int r = ty + j * 8;
    tile[r][tx] = w[(size_t)(d0 + r) * K + k0 + tx];
  }
  __syncthreads();
#pragma unroll
  for (int j = 0; j < 4; ++j) {
    const int r = ty + j * 8;
    wT[(size_t)(k0 + r) * D + d0 + tx] = tile[tx][r];
  }
}

__global__ __launch_bounds__(256) void wsq_kernel(const float* __restrict__ wT,
                                                  float* __restrict__ wsq) {
  const int wave = threadIdx.x >> 6, lane = threadIdx.x & 63;
  const int k = blockIdx.x * 4 + wave;
  const float4 v = *(const float4*)(wT + (size_t)k * D + lane * 4);
  float s = v.x * v.x + v.y * v.y + v.z * v.z + v.w * v.w;
#pragma unroll
  for (int m = 1; m < 64; m <<= 1) s += __shfl_xor(s, m);
  if (lane == 0) wsq[k] = s;
}

__global__ __launch_bounds__(256) void vq_main(
    const float* __restrict__ x, const float* __restrict__ w,
    const float* __restrict__ wT, const float* __restrict__ wsq,
    float* __restrict__ out, float* __restrict__ dwT,
    float* __restrict__ lossAcc) {
  __shared__ float xs[MT * XSTR];   // 66,560 B
  __shared__ float wt[D * NT];      // 65,536 B
  __shared__ float swsq[K];         //  4,096 B
  __shared__ int   sIdx[MT];
  __shared__ float sRed[4];

  const int tid = threadIdx.x;
  const int tx = tid & 15, ty = tid >> 4;   // 16x16 thread grid
  const size_t t0 = (size_t)blockIdx.x * MT;

  // stage x tile (64 tokens x 256 d) + wsq into LDS
  {
    const float4* src = (const float4*)(x + t0 * D);
#pragma unroll
    for (int kk = 0; kk < 16; ++kk) {
      const int f = tid + kk * 256;           // float4 index, 4096 total
      const int row = f >> 6, col4 = f & 63;
      *(float4*)(xs + row * XSTR + (col4 << 2)) = src[f];
    }
#pragma unroll
    for (int kk = 0; kk < 4; ++kk) swsq[tid + kk * 256] = wsq[tid + kk * 256];
  }

  float best[4];
  int bidx[4];
#pragma unroll
  for (int i = 0; i < 4; ++i) { best[i] = -3.4e38f; bidx[i] = 0; }

  for (int chunk = 0; chunk < NCHUNK; ++chunk) {
    const int c0 = chunk * NT;
    __syncthreads();   // previous chunk's compute done before wt overwrite
    {
      const float* wsrc = w + c0;
#pragma unroll
      for (int kk = 0; kk < 16; ++kk) {
        const int f = tid + kk * 256;         // float4 index, 4096 total
        const int dd = f >> 4, col4 = f & 15;
        *(float4*)(wt + dd * NT + (col4 << 2)) =
            *(const float4*)(wsrc + (size_t)dd * K + (col4 << 2));
      }
    }
    __syncthreads();

    float acc[4][4];
#pragma unroll
    for (int i = 0; i < 4; ++i)
#pragma unroll
      for (int j = 0; j < 4; ++j) acc[i][j] = 0.f;

#pragma unroll 2
    for (int d0 = 0; d0 < D; d0 += 4) {
      float4 xv[4];
#pragma unroll
      for (int i = 0; i < 4; ++i)
        xv[i] = *(const float4*)(xs + (ty * 4 + i) * XSTR + d0);
#pragma unroll
      for (int dd = 0; dd < 4; ++dd) {
        const float4 wv = *(const float4*)(wt + (d0 + dd) * NT + (tx << 2));
#pragma unroll
        for (int i = 0; i < 4; ++i) {
          const float xvv = ((const float*)&xv[i])[dd];
          acc[i][0] = fmaf(xvv, wv.x, acc[i][0]);
          acc[i][1] = fmaf(xvv, wv.y, acc[i][1]);
          acc[i][2] = fmaf(xvv, wv.z, acc[i][2]);
          acc[i][3] = fmaf(xvv, wv.w, acc[i][3]);
        }
      }
    }

    // score = 2*s - |w|^2 ; argmax with numpy tie-break (lowest index)
#pragma unroll
    for (int i = 0; i < 4; ++i) {
      float bs = -3.4e38f;
      int bi = 0;
#pragma unroll
      for (int j = 0; j < 4; ++j) {
        const int c = c0 + (tx << 2) + j;
        const float sc = 2.f * acc[i][j] - swsq[c];
        if (sc > bs) { bs = sc; bi = c; }
      }
#pragma unroll
      for (int m = 1; m <= 8; m <<= 1) {
        const float os = __shfl_xor(bs, m);
        const int oi = __shfl_xor(bi, m);
        if (os > bs || (os == bs && oi < bi)) { bs = os; bi = oi; }
      }
      if (bs > best[i] || (bs == best[i] && bi < bidx[i])) { best[i] = bs; bidx[i] = bi; }
    }
  }

  // idx + cluster-size; stash per-token winner for the epilogue
  if (tx == 0) {
#pragma unroll
    for (int i = 0; i < 4; ++i) {
      const int r = ty * 4 + i;
      sIdx[r] = bidx[i];
      out[OFF_IDX + t0 + r] = (float)bidx[i];
      atomicAdd(out + OFF_CS + bidx[i], 1.0f);
    }
  }
  __syncthreads();

  // epilogue: gather quantize (wT rows, L2-resident), loss partial, dw scatter
  float lp = 0.f;
  const int wave = tid >> 6, lane = tid & 63;
  for (int t = 0; t < 16; ++t) {
    const int tt = (t << 2) + wave;       // one wave per token
    const int kbest = sIdx[tt];
    const float* qrow = wT + (size_t)kbest * D;
    float* dwrow = dwT + (size_t)kbest * D;
    float* orow = out + OFF_Q + (t0 + tt) * D;  // offset 1: 4B-misaligned, scalar stores
    const float* xrow = xs + tt * XSTR;
#pragma unroll
    for (int c = 0; c < 4; ++c) {
      const int e = lane + (c << 6);      // contiguous per instruction -> coalesced
      const float q = qrow[e];
      const float xvv = xrow[e];
      orow[e] = q;
      const float dlt = q - xvv;
      lp = fmaf(dlt, dlt, lp);
      atomicAdd(dwrow + e, xvv);
    }
  }
#pragma unroll
  for (int m = 1; m < 64; m <<= 1) lp += __shfl_xor(lp, m);
  if (lane == 0) sRed[wave] = lp;
  __syncthreads();
  if (tid == 0) atomicAdd(lossAcc, sRed[0] + sRed[1] + sRed[2] + sRed[3]);
}

__global__ __launch_bounds__(256) void transpose_dw(const float* __restrict__ dwT,
                                                    float* __restrict__ out) {
  __shared__ float tile[32][33];
  const int d0 = blockIdx.x * 32, k0 = blockIdx.y * 32;
  const int tx = threadIdx.x, ty = threadIdx.y;  // 32x8
#pragma unroll
  for (int j = 0; j < 4; ++j) {
    const int r = ty + j * 8;
    tile[r][tx] = dwT[(size_t)(k0 + r) * D + d0 + tx];
  }
  __syncthreads();
#pragma unroll
  for (int j = 0; j < 4; ++j) {
    const int r = ty + j * 8;
    out[OFF_DW + (size_t)(d0 + r) * K + k0 + tx] = tile[tx][r];
  }
}

__global__ __launch_bounds__(1024) void finalize_kernel(const float* __restrict__ lossAcc,
                                                        float* __restrict__ out) {
  __shared__ float red[16];
  const int tid = threadIdx.x;
  const float c = out[OFF_CS + tid];
  const float avg = c * (1.0f / (float)NTOK);
  float term = avg * logf(avg + 1e-10f);
#pragma unroll
  for (int m = 1; m < 64; m <<= 1) term += __shfl_xor(term, m);
  const int wave = tid >> 6, lane = tid & 63;
  if (lane == 0) red[wave] = term;
  __syncthreads();
  if (tid == 0) {
    float s = 0.f;
#pragma unroll
    for (int i = 0; i < 16; ++i) s += red[i];
    out[OFF_P] = expf(-s);
    out[0] = lossAcc[0] * (1.0f / ((float)NTOK * (float)D));
  }
}

extern "C" void kernel_launch(void* const* d_in, const int* in_sizes, int n_in,
                              void* d_out, int out_size, void* d_ws, size_t ws_size,
                              hipStream_t stream) {
  const float* x = (const float*)d_in[0];
  const float* w = (const float*)d_in[1];
  float* out = (float*)d_out;
  float* wsf = (float*)d_ws;

  float* lossAcc = wsf;                       // 1 float
  float* wsq = wsf + 1024;                    // K floats
  float* wT  = wsf + 2048;                    // K*D floats (1 MB)
  float* dwT = wsf + 2048 + (size_t)K * D;    // K*D floats (1 MB)

  // accumulator regions are 0xAA-poisoned before every timed call
  hipMemsetAsync(lossAcc, 0, sizeof(float), stream);
  hipMemsetAsync(dwT, 0, sizeof(float) * (size_t)K * D, stream);
  hipMemsetAsync(out + OFF_CS, 0, sizeof(float) * K, stream);

  transpose_w<<<dim3(K / 32, D / 32), dim3(32, 8), 0, stream>>>(w, wT);
  wsq_kernel<<<dim3(K / 4), dim3(256), 0, stream>>>(wT, wsq);
  vq_main<<<dim3(NTOK / MT), dim3(256), 0, stream>>>(x, w, wT, wsq, out, dwT, lossAcc);
  transpose_dw<<<dim3(D / 32, K / 32), dim3(32, 8), 0, stream>>>(dwT, out);
  finalize_kernel<<<dim3(1), dim3(1024), 0, stream>>>(lossAcc, out);
}

// Round 2
// 616.809 us; speedup vs baseline: 1.4069x; 1.4069x over previous
//
#include <hip/hip_runtime.h>

// VQ quantize: N=65536 tokens, D=256, K=1024 codes.
// Round 2: bf16 MFMA screening GEMM (32x32x16) + per-token top-2 gap flagging
//          + exact fp32 rescan of flagged tokens + separate epilogue.

#define D 256
#define K 1024
#define NTOK 65536

// flat float32 output offsets (return-order concat)
#define OFF_Q   ((size_t)1)
#define OFF_CS  ((size_t)1 + (size_t)NTOK * D)     // 16777217
#define OFF_DW  (OFF_CS + K)                        // 16778241
#define OFF_IDX (OFF_DW + (size_t)D * K)            // 17040385
#define OFF_P   (OFF_IDX + NTOK)                    // 17105921

#define FLAG_TH  0.5f
#define FLAG_CAP 10240

typedef __attribute__((ext_vector_type(8))) short short8;
typedef __attribute__((ext_vector_type(16))) float f32x16;

__device__ __forceinline__ unsigned short f2bf(float f) {
  // RTNE float->bf16 (inputs are finite)
  unsigned u = __float_as_uint(f);
  return (unsigned short)((u + 0x7FFFu + ((u >> 16) & 1u)) >> 16);
}

// ---- prep: wT fp32 [K][D] + wtbh bf16 [K][D] from w [D][K] ----
__global__ __launch_bounds__(256) void prep_w(const float* __restrict__ w,
                                              float* __restrict__ wT,
                                              unsigned short* __restrict__ wtbh) {
  __shared__ float tile[32][33];
  const int k0 = blockIdx.x * 32, d0 = blockIdx.y * 32;
  const int tx = threadIdx.x, ty = threadIdx.y;  // 32x8
#pragma unroll
  for (int j = 0; j < 4; ++j) {
    const int r = ty + j * 8;
    tile[r][tx] = w[(size_t)(d0 + r) * K + k0 + tx];
  }
  __syncthreads();
#pragma unroll
  for (int j = 0; j < 4; ++j) {
    const int r = ty + j * 8;
    const float v = tile[tx][r];
    wT[(size_t)(k0 + r) * D + d0 + tx] = v;
    wtbh[(size_t)(k0 + r) * D + d0 + tx] = f2bf(v);
  }
}

__global__ __launch_bounds__(256) void wsq_kernel(const float* __restrict__ wT,
                                                  float* __restrict__ wsq) {
  const int wave = threadIdx.x >> 6, lane = threadIdx.x & 63;
  const int k = blockIdx.x * 4 + wave;
  const float4 v = *(const float4*)(wT + (size_t)k * D + lane * 4);
  float s = v.x * v.x + v.y * v.y + v.z * v.z + v.w * v.w;
#pragma unroll
  for (int m = 1; m < 64; m <<= 1) s += __shfl_xor(s, m);
  if (lane == 0) wsq[k] = s;
}

// ---- screening GEMM: bf16 MFMA, fused top-2 argmax ----
// block = 512 thr = 8 waves, each wave 32 tokens (256 tokens/block, grid 256)
__global__ __launch_bounds__(512, 2) void vq_score(
    const float* __restrict__ x, const unsigned short* __restrict__ wtbh,
    const float* __restrict__ wsq, float* __restrict__ out,
    int* __restrict__ flagCnt, int* __restrict__ flagged,
    unsigned long long* __restrict__ keyBuf) {
  __shared__ float swsq[K];
  const int tid = threadIdx.x;
  swsq[tid] = wsq[tid];
  swsq[tid + 512] = wsq[tid + 512];
  __syncthreads();

  const int wv = tid >> 6, lane = tid & 63;
  const int col = lane & 31, hi = lane >> 5;  // A-row/token (col), k-group (hi)
  const int rowG = blockIdx.x * 256 + wv * 32 + col;

  // A fragments: x row in bf16, 16 depth-steps of K=16 (lane holds 8 per step)
  short8 af[16];
  {
    const float* xr = x + (size_t)rowG * D + hi * 8;
#pragma unroll
    for (int s = 0; s < 16; ++s) {
      const float4 f0 = *(const float4*)(xr + s * 16);
      const float4 f1 = *(const float4*)(xr + s * 16 + 4);
      short8 a;
      a[0] = (short)f2bf(f0.x); a[1] = (short)f2bf(f0.y);
      a[2] = (short)f2bf(f0.z); a[3] = (short)f2bf(f0.w);
      a[4] = (short)f2bf(f1.x); a[5] = (short)f2bf(f1.y);
      a[6] = (short)f2bf(f1.z); a[7] = (short)f2bf(f1.w);
      af[s] = a;
    }
  }

  float s1[16], s2[16];
  int i1[16];
#pragma unroll
  for (int r = 0; r < 16; ++r) { s1[r] = -3.4e38f; s2[r] = -3.4e38f; i1[r] = 0; }

  for (int chunk = 0; chunk < 32; ++chunk) {
    const int cc = chunk * 32 + col;  // this lane's code column
    const unsigned short* wr = wtbh + (size_t)cc * D + hi * 8;
    short8 bf[16];
#pragma unroll
    for (int s = 0; s < 16; ++s) bf[s] = *(const short8*)(wr + s * 16);

    f32x16 a0, a1;
#pragma unroll
    for (int r = 0; r < 16; ++r) { a0[r] = 0.f; a1[r] = 0.f; }
#pragma unroll
    for (int s = 0; s < 16; s += 2) {
      a0 = __builtin_amdgcn_mfma_f32_32x32x16_bf16(af[s], bf[s], a0, 0, 0, 0);
      a1 = __builtin_amdgcn_mfma_f32_32x32x16_bf16(af[s + 1], bf[s + 1], a1, 0, 0, 0);
    }

    const float wq = swsq[cc];
#pragma unroll
    for (int r = 0; r < 16; ++r) {
      const float sc = fmaf(2.f, a0[r] + a1[r], -wq);
      const bool gt = sc > s1[r];
      s2[r] = fmaxf(s2[r], gt ? s1[r] : sc);
      if (gt) { s1[r] = sc; i1[r] = cc; }
    }
  }

  // cross-lane top-2 merge (masks 1..16 keep lane>>5 fixed -> same token set)
#pragma unroll
  for (int m = 1; m <= 16; m <<= 1) {
#pragma unroll
    for (int r = 0; r < 16; ++r) {
      const float os1 = __shfl_xor(s1[r], m);
      const int   oi1 = __shfl_xor(i1[r], m);
      const float os2 = __shfl_xor(s2[r], m);
      const bool take = (os1 > s1[r]) || (os1 == s1[r] && oi1 < i1[r]);
      const float loser = take ? s1[r] : os1;
      if (take) { s1[r] = os1; i1[r] = oi1; }
      s2[r] = fmaxf(fmaxf(s2[r], os2), loser);
    }
  }

  if (col == 0) {
    const size_t tb = (size_t)blockIdx.x * 256 + wv * 32;
#pragma unroll
    for (int r = 0; r < 16; ++r) {
      const int row = (r & 3) + 8 * (r >> 2) + 4 * hi;  // C/D row map (m74/m101)
      const size_t g = tb + row;
      out[OFF_IDX + g] = (float)i1[r];
      if (s1[r] - s2[r] < FLAG_TH) {
        const int slot = atomicAdd(flagCnt, 1);
        if (slot < FLAG_CAP) {
          flagged[slot] = (int)g;
          keyBuf[slot] = 0ull;
        }
      }
    }
  }
}

// ---- exact fp32 rescan of flagged tokens (batched, code-chunked) ----
__global__ __launch_bounds__(256) void vq_fixup(
    const float* __restrict__ x, const float* __restrict__ wT,
    const float* __restrict__ wsq, const int* __restrict__ flagCnt,
    const int* __restrict__ flagged, unsigned long long* __restrict__ keyBuf) {
  __shared__ float ws32[32][260];  // pad 260: (4*ci+dg) bank spread
  __shared__ float xs[D];
  const int tid = threadIdx.x;
  const int cc = blockIdx.x & 31, j = blockIdx.x >> 5;
#pragma unroll
  for (int r = 0; r < 32; ++r) ws32[r][tid] = wT[(size_t)(cc * 32 + r) * D + tid];

  int F = *flagCnt;
  if (F > FLAG_CAP) F = FLAG_CAP;

  const int ci = tid >> 3, dg = tid & 7, c = cc * 32 + ci;
  const float wq = wsq[c];

  for (int slot = j; slot < F; slot += 32) {
    const int t = flagged[slot];
    __syncthreads();
    xs[tid] = x[(size_t)t * D + tid];
    __syncthreads();
    float dot = 0.f;
#pragma unroll
    for (int i = 0; i < 32; ++i) {
      const int d = dg + 8 * i;
      dot = fmaf(xs[d], ws32[ci][d], dot);
    }
    dot += __shfl_xor(dot, 1);
    dot += __shfl_xor(dot, 2);
    dot += __shfl_xor(dot, 4);
    if (dg == 0) {
      const float sc = fmaf(2.f, dot, -wq);
      unsigned u = __float_as_uint(sc);
      u = (u & 0x80000000u) ? ~u : (u | 0x80000000u);
      const unsigned long long key =
          ((unsigned long long)u << 32) | (unsigned long long)(1023 - c);
      atomicMax(keyBuf + slot, key);
    }
  }
}

__global__ __launch_bounds__(256) void vq_fixfin(
    const int* __restrict__ flagCnt, const int* __restrict__ flagged,
    const unsigned long long* __restrict__ keyBuf, float* __restrict__ out) {
  int F = *flagCnt;
  if (F > FLAG_CAP) F = FLAG_CAP;
  for (int slot = blockIdx.x * 256 + threadIdx.x; slot < F; slot += gridDim.x * 256) {
    const int t = flagged[slot];
    const int c = 1023 - (int)(keyBuf[slot] & 0xFFFFFFFFull);
    out[OFF_IDX + t] = (float)c;
  }
}

// ---- epilogue: gather quantize, loss, dw atomics, cluster counts ----
__global__ __launch_bounds__(256) void vq_epilogue(
    const float* __restrict__ x, const float* __restrict__ wT,
    float* __restrict__ out, float* __restrict__ dwT,
    float* __restrict__ lossAcc) {
  __shared__ float sRed[4];
  const int tid = threadIdx.x, wave = tid >> 6, lane = tid & 63;
  const size_t t0 = (size_t)blockIdx.x * 64;
  float lp = 0.f;
  for (int t = 0; t < 16; ++t) {
    const size_t g = t0 + (size_t)t * 4 + wave;  // one wave per token
    const int k = (int)out[OFF_IDX + g];
    const float* qrow = wT + (size_t)k * D;
    const float* xrow = x + g * D;
    float* orow = out + OFF_Q + g * D;  // 4B-misaligned for float4 -> scalar
    float* dwrow = dwT + (size_t)k * D;
#pragma unroll
    for (int c = 0; c < 4; ++c) {
      const int e = lane + (c << 6);
      const float q = qrow[e], xv = xrow[e];
      orow[e] = q;
      const float dlt = q - xv;
      lp = fmaf(dlt, dlt, lp);
      atomicAdd(dwrow + e, xv);
    }
    if (lane == 0) atomicAdd(out + OFF_CS + k, 1.0f);
  }
#pragma unroll
  for (int m = 1; m < 64; m <<= 1) lp += __shfl_xor(lp, m);
  if (lane == 0) sRed[wave] = lp;
  __syncthreads();
  if (tid == 0) atomicAdd(lossAcc, sRed[0] + sRed[1] + sRed[2] + sRed[3]);
}

__global__ __launch_bounds__(256) void transpose_dw(const float* __restrict__ dwT,
                                                    float* __restrict__ out) {
  __shared__ float tile[32][33];
  const int d0 = blockIdx.x * 32, k0 = blockIdx.y * 32;
  const int tx = threadIdx.x, ty = threadIdx.y;  // 32x8
#pragma unroll
  for (int j = 0; j < 4; ++j) {
    const int r = ty + j * 8;
    tile[r][tx] = dwT[(size_t)(k0 + r) * D + d0 + tx];
  }
  __syncthreads();
#pragma unroll
  for (int j = 0; j < 4; ++j) {
    const int r = ty + j * 8;
    out[OFF_DW + (size_t)(d0 + r) * K + k0 + tx] = tile[tx][r];
  }
}

__global__ __launch_bounds__(1024) void finalize_kernel(const float* __restrict__ lossAcc,
                                                        float* __restrict__ out) {
  __shared__ float red[16];
  const int tid = threadIdx.x;
  const float c = out[OFF_CS + tid];
  const float avg = c * (1.0f / (float)NTOK);
  float term = avg * logf(avg + 1e-10f);
#pragma unroll
  for (int m = 1; m < 64; m <<= 1) term += __shfl_xor(term, m);
  const int wave = tid >> 6, lane = tid & 63;
  if (lane == 0) red[wave] = term;
  __syncthreads();
  if (tid == 0) {
    float s = 0.f;
#pragma unroll
    for (int i = 0; i < 16; ++i) s += red[i];
    out[OFF_P] = expf(-s);
    out[0] = lossAcc[0] * (1.0f / ((float)NTOK * (float)D));
  }
}

extern "C" void kernel_launch(void* const* d_in, const int* in_sizes, int n_in,
                              void* d_out, int out_size, void* d_ws, size_t ws_size,
                              hipStream_t stream) {
  const float* x = (const float*)d_in[0];
  const float* w = (const float*)d_in[1];
  float* out = (float*)d_out;
  char* wsb = (char*)d_ws;

  // ws layout (bytes)
  float* lossAcc = (float*)(wsb + 0);
  int* flagCnt = (int*)(wsb + 4);
  float* wsq = (float*)(wsb + 256);                            // 4 KB
  float* wT = (float*)(wsb + 8192);                            // 1 MB
  unsigned short* wtbh = (unsigned short*)(wsb + 1056768);     // 512 KB
  float* dwT = (float*)(wsb + 1581056);                        // 1 MB
  int* flagged = (int*)(wsb + 2629632);                        // 40 KB
  unsigned long long* keyBuf = (unsigned long long*)(wsb + 2670592);  // 80 KB

  // accumulator regions are 0xAA-poisoned before every timed call
  hipMemsetAsync(wsb, 0, 8, stream);                            // lossAcc+flagCnt
  hipMemsetAsync(dwT, 0, sizeof(float) * (size_t)K * D, stream);
  hipMemsetAsync(out + OFF_CS, 0, sizeof(float) * K, stream);

  prep_w<<<dim3(K / 32, D / 32), dim3(32, 8), 0, stream>>>(w, wT, wtbh);
  wsq_kernel<<<dim3(K / 4), dim3(256), 0, stream>>>(wT, wsq);
  vq_score<<<dim3(NTOK / 256), dim3(512), 0, stream>>>(x, wtbh, wsq, out,
                                                       flagCnt, flagged, keyBuf);
  vq_fixup<<<dim3(1024), dim3(256), 0, stream>>>(x, wT, wsq, flagCnt, flagged, keyBuf);
  vq_fixfin<<<dim3(64), dim3(256), 0, stream>>>(flagCnt, flagged, keyBuf, out);
  vq_epilogue<<<dim3(NTOK / 64), dim3(256), 0, stream>>>(x, wT, out, dwT, lossAcc);
  transpose_dw<<<dim3(D / 32, K / 32), dim3(32, 8), 0, stream>>>(dwT, out);
  finalize_kernel<<<dim3(1), dim3(1024), 0, stream>>>(lossAcc, out);
}

// Round 3
// 463.956 us; speedup vs baseline: 1.8704x; 1.3295x over previous
//
#include <hip/hip_runtime.h>

// VQ quantize: N=65536 tokens, D=256, K=1024 codes.
// Round 3: bf16x2 (split-precision) MFMA screen + tight flag threshold,
//          contention-free fixup (private keys + reduce),
//          counting-sort epilogue (gather-free, 8x fewer atomics).

#define D 256
#define K 1024
#define NTOK 65536

// flat float32 output offsets (return-order concat)
#define OFF_Q   ((size_t)1)
#define OFF_CS  ((size_t)1 + (size_t)NTOK * D)     // 16777217
#define OFF_DW  (OFF_CS + K)                        // 16778241
#define OFF_IDX (OFF_DW + (size_t)D * K)            // 17040385
#define OFF_P   (OFF_IDX + NTOK)                    // 17105921

#define FLAG_TH  0.05f
#define FLAG_CAP 8192

typedef __attribute__((ext_vector_type(8))) short short8;
typedef __attribute__((ext_vector_type(16))) float f32x16;

__device__ __forceinline__ unsigned short f2bf(float f) {
  unsigned u = __float_as_uint(f);
  return (unsigned short)((u + 0x7FFFu + ((u >> 16) & 1u)) >> 16);
}
__device__ __forceinline__ float bf2f(unsigned short h) {
  return __uint_as_float(((unsigned)h) << 16);
}

// ---- prep: wT fp32 [K][D]; wh/wl bf16 in fragment-major chunk layout ----
// frag-major elem index for (k,d): chunk=k>>5, col=k&31, s=d>>4, hi=(d>>3)&1, b=d&7
//   idx = chunk*8192 + ((s*2+hi)*32 + col)*8 + b
__global__ __launch_bounds__(256) void prep_w(const float* __restrict__ w,
                                              float* __restrict__ wT,
                                              unsigned short* __restrict__ whG,
                                              unsigned short* __restrict__ wlG) {
  __shared__ float tile[32][33];
  const int k0 = blockIdx.x * 32, d0 = blockIdx.y * 32;
  const int tx = threadIdx.x, ty = threadIdx.y;  // 32x8
#pragma unroll
  for (int j = 0; j < 4; ++j) {
    const int r = ty + j * 8;
    tile[r][tx] = w[(size_t)(d0 + r) * K + k0 + tx];
  }
  __syncthreads();
#pragma unroll
  for (int j = 0; j < 4; ++j) {
    const int r = ty + j * 8;
    const int k = k0 + r, d = d0 + tx;
    const float v = tile[tx][r];
    wT[(size_t)k * D + d] = v;
    const unsigned short h = f2bf(v);
    const unsigned short l = f2bf(v - bf2f(h));
    const size_t idx = (size_t)(k >> 5) * 8192 +
                       (size_t)(((d >> 4) * 2 + ((d >> 3) & 1)) * 32 + (k & 31)) * 8 +
                       (d & 7);
    whG[idx] = h;
    wlG[idx] = l;
  }
}

__global__ __launch_bounds__(256) void wsq_kernel(const float* __restrict__ wT,
                                                  float* __restrict__ wsq) {
  const int wave = threadIdx.x >> 6, lane = threadIdx.x & 63;
  const int k = blockIdx.x * 4 + wave;
  const float4 v = *(const float4*)(wT + (size_t)k * D + lane * 4);
  float s = v.x * v.x + v.y * v.y + v.z * v.z + v.w * v.w;
#pragma unroll
  for (int m = 1; m < 64; m <<= 1) s += __shfl_xor(s, m);
  if (lane == 0) wsq[k] = s;
}

// ---- bf16x2 screening GEMM: 3 MFMA chains (hh, hl, lh), fused top-2 ----
// block = 256 thr (4 waves x 32 tokens = 128 tokens), grid 512, 2 blocks/CU
__global__ __launch_bounds__(256, 2) void vq_score(
    const float* __restrict__ x,
    const unsigned short* __restrict__ whG, const unsigned short* __restrict__ wlG,
    const float* __restrict__ wsq, float* __restrict__ out,
    int* __restrict__ idxInt, int* __restrict__ flagCnt, int* __restrict__ flagged) {
  __shared__ short whS[2][8192];  // 2 x 16 KB, frag-major chunk
  __shared__ short wlS[2][8192];
  __shared__ float swsq[K];

  const int tid = threadIdx.x;
#pragma unroll
  for (int j = 0; j < 4; ++j) swsq[tid + j * 256] = wsq[tid + j * 256];

  const int wv = tid >> 6, lane = tid & 63;
  const int col = lane & 31, hi = lane >> 5;
  const int rowG = blockIdx.x * 128 + wv * 32 + col;

  // A fragments (token rows), hi/lo split
  short8 ah[16], al[16];
  {
    const float* xr = x + (size_t)rowG * D + hi * 8;
#pragma unroll
    for (int s = 0; s < 16; ++s) {
      const float4 f0 = *(const float4*)(xr + s * 16);
      const float4 f1 = *(const float4*)(xr + s * 16 + 4);
      const float fv[8] = {f0.x, f0.y, f0.z, f0.w, f1.x, f1.y, f1.z, f1.w};
      short8 a, b;
#pragma unroll
      for (int e = 0; e < 8; ++e) {
        const unsigned short h = f2bf(fv[e]);
        a[e] = (short)h;
        b[e] = (short)f2bf(fv[e] - bf2f(h));
      }
      ah[s] = a;
      al[s] = b;
    }
  }

  // stage chunk -> LDS buf (linear copy thanks to frag-major global layout)
  auto stage = [&](int chunk, int buf) {
    const short8* srcH = (const short8*)(whG + (size_t)chunk * 8192);
    const short8* srcL = (const short8*)(wlG + (size_t)chunk * 8192);
    short8* dstH = (short8*)whS[buf];
    short8* dstL = (short8*)wlS[buf];
#pragma unroll
    for (int j = 0; j < 4; ++j) {
      dstH[tid + j * 256] = srcH[tid + j * 256];
      dstL[tid + j * 256] = srcL[tid + j * 256];
    }
  };

  float s1[16], s2[16];
  int i1[16];
#pragma unroll
  for (int r = 0; r < 16; ++r) { s1[r] = -3.4e38f; s2[r] = -3.4e38f; i1[r] = 0; }

  stage(0, 0);
  __syncthreads();

  for (int chunk = 0; chunk < 32; ++chunk) {
    const int cur = chunk & 1;
    if (chunk + 1 < 32) stage(chunk + 1, cur ^ 1);

    const short* bhB = whS[cur];
    const short* blB = wlS[cur];
    f32x16 ahh, ahl, alh;
#pragma unroll
    for (int r = 0; r < 16; ++r) { ahh[r] = 0.f; ahl[r] = 0.f; alh[r] = 0.f; }
#pragma unroll
    for (int s = 0; s < 16; ++s) {
      const int off = ((s * 2 + hi) << 8) + (col << 3);  // shorts; 16B-aligned
      const short8 bh = *(const short8*)(bhB + off);
      const short8 bl = *(const short8*)(blB + off);
      ahh = __builtin_amdgcn_mfma_f32_32x32x16_bf16(ah[s], bh, ahh, 0, 0, 0);
      ahl = __builtin_amdgcn_mfma_f32_32x32x16_bf16(ah[s], bl, ahl, 0, 0, 0);
      alh = __builtin_amdgcn_mfma_f32_32x32x16_bf16(al[s], bh, alh, 0, 0, 0);
    }

    const int cc = chunk * 32 + col;
    const float wq = swsq[cc];
#pragma unroll
    for (int r = 0; r < 16; ++r) {
      const float sc = fmaf(2.f, ahh[r] + ahl[r] + alh[r], -wq);
      const bool gt = sc > s1[r];
      s2[r] = fmaxf(s2[r], gt ? s1[r] : sc);
      if (gt) { s1[r] = sc; i1[r] = cc; }
    }
    __syncthreads();
  }

  // cross-lane top-2 merge (masks 1..16 keep hi fixed -> same token set)
#pragma unroll
  for (int m = 1; m <= 16; m <<= 1) {
#pragma unroll
    for (int r = 0; r < 16; ++r) {
      const float os1 = __shfl_xor(s1[r], m);
      const int   oi1 = __shfl_xor(i1[r], m);
      const float os2 = __shfl_xor(s2[r], m);
      const bool take = (os1 > s1[r]) || (os1 == s1[r] && oi1 < i1[r]);
      const float loser = take ? s1[r] : os1;
      if (take) { s1[r] = os1; i1[r] = oi1; }
      s2[r] = fmaxf(fmaxf(s2[r], os2), loser);
    }
  }

  if (col == 0) {
    const size_t tb = (size_t)blockIdx.x * 128 + wv * 32;
#pragma unroll
    for (int r = 0; r < 16; ++r) {
      const int row = (r & 3) + 8 * (r >> 2) + 4 * hi;  // C/D row map (m74/m101)
      const size_t g = tb + row;
      idxInt[g] = i1[r];
      out[OFF_IDX + g] = (float)i1[r];
      if (s1[r] - s2[r] < FLAG_TH) {
        const int slot = atomicAdd(flagCnt, 1);
        if (slot < FLAG_CAP) flagged[slot] = (int)g;
      }
    }
  }
}

// ---- exact fp32 rescan: private keys per (slot, chunk), no contention ----
__global__ __launch_bounds__(256) void vq_fixup(
    const float* __restrict__ x, const float* __restrict__ wT,
    const float* __restrict__ wsq, const int* __restrict__ flagCnt,
    const int* __restrict__ flagged, unsigned long long* __restrict__ keyBuf) {
  __shared__ float ws32[32 * 264];  // stride 264: bank = (8*ci+dg+8i)&31, 2-way max
  __shared__ float xs[D];
  __shared__ unsigned long long wred[4];
  const int tid = threadIdx.x;
  const int cc = blockIdx.x & 31, j0 = blockIdx.x >> 5;  // 32 chunks x 64 groups
#pragma unroll
  for (int r = 0; r < 32; ++r)
    ws32[r * 264 + tid] = wT[(size_t)(cc * 32 + r) * D + tid];
  int F = *flagCnt;
  if (F > FLAG_CAP) F = FLAG_CAP;
  const int ci = tid >> 3, dg = tid & 7, c = cc * 32 + ci;
  const float wq = wsq[c];

  for (int slot = j0; slot < F; slot += 64) {
    const int t = flagged[slot];
    __syncthreads();
    xs[tid] = x[(size_t)t * D + tid];
    __syncthreads();
    float dot = 0.f;
#pragma unroll
    for (int i = 0; i < 32; ++i)
      dot = fmaf(xs[dg + 8 * i], ws32[ci * 264 + dg + 8 * i], dot);
    dot += __shfl_xor(dot, 1);
    dot += __shfl_xor(dot, 2);
    dot += __shfl_xor(dot, 4);
    unsigned long long key = 0ull;
    if (dg == 0) {
      const float sc = fmaf(2.f, dot, -wq);
      unsigned u = __float_as_uint(sc);
      u = (u & 0x80000000u) ? ~u : (u | 0x80000000u);
      key = ((unsigned long long)u << 32) | (unsigned)(1023 - c);
    }
#pragma unroll
    for (int m = 8; m <= 32; m <<= 1) {
      const unsigned long long o = __shfl_xor(key, m);
      if (o > key) key = o;
    }
    if ((tid & 63) == 0) wred[tid >> 6] = key;
    __syncthreads();
    if (tid == 0) {
      unsigned long long b = wred[0];
      if (wred[1] > b) b = wred[1];
      if (wred[2] > b) b = wred[2];
      if (wred[3] > b) b = wred[3];
      keyBuf[(size_t)slot * 32 + cc] = b;
    }
  }
}

__global__ __launch_bounds__(256) void vq_fixfin(
    const int* __restrict__ flagCnt, const int* __restrict__ flagged,
    const unsigned long long* __restrict__ keyBuf, int* __restrict__ idxInt,
    float* __restrict__ out) {
  int F = *flagCnt;
  if (F > FLAG_CAP) F = FLAG_CAP;
  for (int slot = blockIdx.x * 256 + threadIdx.x; slot < F; slot += 4096) {
    unsigned long long b = 0ull;
#pragma unroll
    for (int j = 0; j < 32; ++j) {
      const unsigned long long v = keyBuf[(size_t)slot * 32 + j];
      if (v > b) b = v;
    }
    const int c = 1023 - (int)(b & 0xFFFFFFFFull);
    const int t = flagged[slot];
    idxInt[t] = c;
    out[OFF_IDX + t] = (float)c;
  }
}

// ---- counting sort: count -> scan -> scatter ----
__global__ __launch_bounds__(256) void vq_count(const int* __restrict__ idxInt,
                                                int* __restrict__ countsInt) {
  const int t = blockIdx.x * 256 + threadIdx.x;
  atomicAdd(countsInt + idxInt[t], 1);
}

__global__ __launch_bounds__(1024) void vq_scan(const int* __restrict__ countsInt,
                                                int* __restrict__ bucketStart,
                                                int* __restrict__ cursorInt,
                                                float* __restrict__ out) {
  __shared__ int sc[1024];
  const int tid = threadIdx.x;
  const int c = countsInt[tid];
  out[OFF_CS + tid] = (float)c;
  sc[tid] = c;
  __syncthreads();
  for (int off = 1; off < 1024; off <<= 1) {
    int v = 0;
    if (tid >= off) v = sc[tid - off];
    __syncthreads();
    if (tid >= off) sc[tid] += v;
    __syncthreads();
  }
  bucketStart[tid] = sc[tid] - c;  // exclusive
  cursorInt[tid] = 0;
}

__global__ __launch_bounds__(256) void vq_scatter(const int* __restrict__ idxInt,
                                                  const int* __restrict__ bucketStart,
                                                  int* __restrict__ cursorInt,
                                                  int* __restrict__ sortedTok) {
  const int t = blockIdx.x * 256 + threadIdx.x;
  const int k = idxInt[t];
  const int pos = atomicAdd(cursorInt + k, 1);
  sortedTok[bucketStart[k] + pos] = t;
}

// ---- process buckets: quantize write, loss, dw accumulation ----
// grid = 1024 codes x 8 splits; one atomicAdd per (block, thread) into dwT
__global__ __launch_bounds__(256) void vq_process(
    const float* __restrict__ x, const float* __restrict__ wT,
    const int* __restrict__ countsInt, const int* __restrict__ bucketStart,
    const int* __restrict__ sortedTok, float* __restrict__ out,
    float* __restrict__ dwT, float* __restrict__ lossAcc) {
  __shared__ float sRed[4];
  const int tid = threadIdx.x;
  const int k = blockIdx.x >> 3, j = blockIdx.x & 7;
  const int cnt = countsInt[k], start = bucketStart[k];
  const int lo = start + ((cnt * j) >> 3);
  const int hiP = start + ((cnt * (j + 1)) >> 3);
  if (lo >= hiP) return;
  const float wv = wT[(size_t)k * D + tid];
  float acc = 0.f, lp = 0.f;
  int t = sortedTok[lo];
  for (int p = lo; p < hiP; ++p) {
    const int tn = (p + 1 < hiP) ? sortedTok[p + 1] : 0;
    const float xv = x[(size_t)t * D + tid];
    out[OFF_Q + (size_t)t * D + tid] = wv;
    acc += xv;
    const float dl = wv - xv;
    lp = fmaf(dl, dl, lp);
    t = tn;
  }
  atomicAdd(dwT + (size_t)k * D + tid, acc);
  const int wave = tid >> 6, lane = tid & 63;
#pragma unroll
  for (int m = 1; m < 64; m <<= 1) lp += __shfl_xor(lp, m);
  if (lane == 0) sRed[wave] = lp;
  __syncthreads();
  if (tid == 0) atomicAdd(lossAcc, sRed[0] + sRed[1] + sRed[2] + sRed[3]);
}

__global__ __launch_bounds__(256) void transpose_dw(const float* __restrict__ dwT,
                                                    float* __restrict__ out) {
  __shared__ float tile[32][33];
  const int d0 = blockIdx.x * 32, k0 = blockIdx.y * 32;
  const int tx = threadIdx.x, ty = threadIdx.y;  // 32x8
#pragma unroll
  for (int j = 0; j < 4; ++j) {
    const int r = ty + j * 8;
    tile[r][tx] = dwT[(size_t)(k0 + r) * D + d0 + tx];
  }
  __syncthreads();
#pragma unroll
  for (int j = 0; j < 4; ++j) {
    const int r = ty + j * 8;
    out[OFF_DW + (size_t)(d0 + r) * K + k0 + tx] = tile[tx][r];
  }
}

__global__ __launch_bounds__(1024) void finalize_kernel(const float* __restrict__ lossAcc,
                                                        float* __restrict__ out) {
  __shared__ float red[16];
  const int tid = threadIdx.x;
  const float c = out[OFF_CS + tid];
  const float avg = c * (1.0f / (float)NTOK);
  float term = avg * logf(avg + 1e-10f);
#pragma unroll
  for (int m = 1; m < 64; m <<= 1) term += __shfl_xor(term, m);
  const int wave = tid >> 6, lane = tid & 63;
  if (lane == 0) red[wave] = term;
  __syncthreads();
  if (tid == 0) {
    float s = 0.f;
#pragma unroll
    for (int i = 0; i < 16; ++i) s += red[i];
    out[OFF_P] = expf(-s);
    out[0] = lossAcc[0] * (1.0f / ((float)NTOK * (float)D));
  }
}

extern "C" void kernel_launch(void* const* d_in, const int* in_sizes, int n_in,
                              void* d_out, int out_size, void* d_ws, size_t ws_size,
                              hipStream_t stream) {
  const float* x = (const float*)d_in[0];
  const float* w = (const float*)d_in[1];
  float* out = (float*)d_out;
  char* wsb = (char*)d_ws;

  // ws layout (bytes)
  float* lossAcc   = (float*)(wsb + 0);
  int*   flagCnt   = (int*)(wsb + 4);
  float* wsq       = (float*)(wsb + 256);
  int*   countsInt = (int*)(wsb + 8192);
  int*   bucketStart = (int*)(wsb + 12288);
  int*   cursorInt = (int*)(wsb + 16384);
  int*   idxInt    = (int*)(wsb + 20480);                        // 256 KB
  int*   sortedTok = (int*)(wsb + 282624);                       // 256 KB
  int*   flagged   = (int*)(wsb + 544768);                       // 32 KB
  unsigned long long* keyBuf = (unsigned long long*)(wsb + 577536);  // 2 MB
  float* wT        = (float*)(wsb + 2674688);                    // 1 MB
  unsigned short* whG = (unsigned short*)(wsb + 3723264);        // 512 KB
  unsigned short* wlG = (unsigned short*)(wsb + 4247552);        // 512 KB
  float* dwT       = (float*)(wsb + 4771840);                    // 1 MB

  // zero accumulators (d_ws is 0xAA-poisoned before every timed call)
  hipMemsetAsync(wsb, 0, 16384, stream);                         // ctrl+wsq+counts
  hipMemsetAsync(dwT, 0, sizeof(float) * (size_t)K * D, stream);

  prep_w<<<dim3(K / 32, D / 32), dim3(32, 8), 0, stream>>>(w, wT, whG, wlG);
  wsq_kernel<<<dim3(K / 4), dim3(256), 0, stream>>>(wT, wsq);
  vq_score<<<dim3(NTOK / 128), dim3(256), 0, stream>>>(x, whG, wlG, wsq, out,
                                                       idxInt, flagCnt, flagged);
  vq_fixup<<<dim3(2048), dim3(256), 0, stream>>>(x, wT, wsq, flagCnt, flagged, keyBuf);
  vq_fixfin<<<dim3(16), dim3(256), 0, stream>>>(flagCnt, flagged, keyBuf, idxInt, out);
  vq_count<<<dim3(NTOK / 256), dim3(256), 0, stream>>>(idxInt, countsInt);
  vq_scan<<<dim3(1), dim3(1024), 0, stream>>>(countsInt, bucketStart, cursorInt, out);
  vq_scatter<<<dim3(NTOK / 256), dim3(256), 0, stream>>>(idxInt, bucketStart,
                                                         cursorInt, sortedTok);
  vq_process<<<dim3(K * 8), dim3(256), 0, stream>>>(x, wT, countsInt, bucketStart,
                                                    sortedTok, out, dwT, lossAcc);
  transpose_dw<<<dim3(D / 32, K / 32), dim3(32, 8), 0, stream>>>(dwT, out);
  finalize_kernel<<<dim3(1), dim3(1024), 0, stream>>>(lossAcc, out);
}

// Round 5
// 387.152 us; speedup vs baseline: 2.2415x; 1.1984x over previous
//
#include <hip/hip_runtime.h>

// VQ quantize: N=65536 tokens, D=256, K=1024 codes.
// Round 4 (resubmit; round-4 bench was an infra timeout, kernel never ran):
//   vq_score with async global_load_lds staging (no vmcnt stall before MFMAs)
//   + fused quantize-row write; balanced sorted-order dw+loss kernel
//   (replaces per-code vq_process); fixfin repairs idx/counts/rows.

#define D 256
#define K 1024
#define NTOK 65536

// flat float32 output offsets (return-order concat)
#define OFF_Q   ((size_t)1)
#define OFF_CS  ((size_t)1 + (size_t)NTOK * D)     // 16777217
#define OFF_DW  (OFF_CS + K)                        // 16778241
#define OFF_IDX (OFF_DW + (size_t)D * K)            // 17040385
#define OFF_P   (OFF_IDX + NTOK)                    // 17105921

#define FLAG_TH  0.05f
#define FLAG_CAP 8192

typedef __attribute__((ext_vector_type(8))) short short8;
typedef __attribute__((ext_vector_type(16))) float f32x16;

__device__ __forceinline__ unsigned short f2bf(float f) {
  unsigned u = __float_as_uint(f);
  return (unsigned short)((u + 0x7FFFu + ((u >> 16) & 1u)) >> 16);
}
__device__ __forceinline__ float bf2f(unsigned short h) {
  return __uint_as_float(((unsigned)h) << 16);
}

// async global->LDS, 16B per lane; LDS dest = wave-uniform base + lane*16
__device__ __forceinline__ void gload_lds16(void* g, void* l) {
  __builtin_amdgcn_global_load_lds(
      (__attribute__((address_space(1))) unsigned int*)g,
      (__attribute__((address_space(3))) unsigned int*)l, 16, 0, 0);
}

// ---- prep: wT fp32 [K][D]; wBG bf16 hi/lo in per-chunk {hi 8192; lo 8192} ----
// frag idx for (k,d): s=d>>4, hi=(d>>3)&1, col=k&31, b=d&7 ->
//   ((s*2+hi)*32 + col)*8 + b  within 8192; chunk = k>>5
__global__ __launch_bounds__(256) void prep_w(const float* __restrict__ w,
                                              float* __restrict__ wT,
                                              unsigned short* __restrict__ wBG) {
  __shared__ float tile[32][33];
  const int k0 = blockIdx.x * 32, d0 = blockIdx.y * 32;
  const int tx = threadIdx.x, ty = threadIdx.y;  // 32x8
#pragma unroll
  for (int j = 0; j < 4; ++j) {
    const int r = ty + j * 8;
    tile[r][tx] = w[(size_t)(d0 + r) * K + k0 + tx];
  }
  __syncthreads();
#pragma unroll
  for (int j = 0; j < 4; ++j) {
    const int r = ty + j * 8;
    const int k = k0 + r, d = d0 + tx;
    const float v = tile[tx][r];
    wT[(size_t)k * D + d] = v;
    const unsigned short h = f2bf(v);
    const unsigned short l = f2bf(v - bf2f(h));
    const size_t frag = (size_t)(((d >> 4) * 2 + ((d >> 3) & 1)) * 32 + (k & 31)) * 8 +
                        (d & 7);
    const size_t base = (size_t)(k >> 5) * 16384;
    wBG[base + frag] = h;
    wBG[base + 8192 + frag] = l;
  }
}

__global__ __launch_bounds__(256) void wsq_kernel(const float* __restrict__ wT,
                                                  float* __restrict__ wsq) {
  const int wave = threadIdx.x >> 6, lane = threadIdx.x & 63;
  const int k = blockIdx.x * 4 + wave;
  const float4 v = *(const float4*)(wT + (size_t)k * D + lane * 4);
  float s = v.x * v.x + v.y * v.y + v.z * v.z + v.w * v.w;
#pragma unroll
  for (int m = 1; m < 64; m <<= 1) s += __shfl_xor(s, m);
  if (lane == 0) wsq[k] = s;
}

// ---- bf16x2 screening GEMM + fused top-2 + fused quantize write ----
// block = 256 thr (4 waves x 32 tokens), grid 512
__global__ __launch_bounds__(256, 2) void vq_score(
    const float* __restrict__ x, unsigned short* __restrict__ wBG,
    const float* __restrict__ wsq, const float* __restrict__ wT,
    float* __restrict__ out, int* __restrict__ idxInt, int* __restrict__ countsInt,
    int* __restrict__ flagCnt, int* __restrict__ flagged) {
  __shared__ short sB[2][16384];  // [buf]{hi 8192; lo 8192} shorts, 64 KB
  __shared__ float swsq[K];

  const int tid = threadIdx.x;
#pragma unroll
  for (int j = 0; j < 4; ++j) swsq[tid + j * 256] = wsq[tid + j * 256];

  const int wv = tid >> 6, lane = tid & 63;
  const int col = lane & 31, hi = lane >> 5;
  const int rowG = blockIdx.x * 128 + wv * 32 + col;

  // stage one 32KB chunk (hi+lo) via async DMA; wave wv owns 8KB slice
  auto stage = [&](int chunk, int buf) {
    unsigned short* src = wBG + (size_t)chunk * 16384 + wv * 4096 + lane * 8;
    short* dst = &sB[buf][wv * 4096];
#pragma unroll
    for (int j = 0; j < 8; ++j)
      gload_lds16(src + j * 512, dst + j * 512);
  };

  stage(0, 0);

  // A fragments (token rows), hi/lo split — overlaps with chunk-0 DMA
  short8 ah[16], al[16];
  {
    const float* xr = x + (size_t)rowG * D + hi * 8;
#pragma unroll
    for (int s = 0; s < 16; ++s) {
      const float4 f0 = *(const float4*)(xr + s * 16);
      const float4 f1 = *(const float4*)(xr + s * 16 + 4);
      const float fv[8] = {f0.x, f0.y, f0.z, f0.w, f1.x, f1.y, f1.z, f1.w};
      short8 a, b;
#pragma unroll
      for (int e = 0; e < 8; ++e) {
        const unsigned short h = f2bf(fv[e]);
        a[e] = (short)h;
        b[e] = (short)f2bf(fv[e] - bf2f(h));
      }
      ah[s] = a;
      al[s] = b;
    }
  }

  float s1[16], s2[16];
  int i1[16];
#pragma unroll
  for (int r = 0; r < 16; ++r) { s1[r] = -3.4e38f; s2[r] = -3.4e38f; i1[r] = 0; }

  __syncthreads();  // chunk 0 resident

  for (int chunk = 0; chunk < 32; ++chunk) {
    const int cur = chunk & 1;
    if (chunk + 1 < 32) stage(chunk + 1, cur ^ 1);  // async, drains at barrier

    const short* bhB = sB[cur];
    const short* blB = sB[cur] + 8192;
    f32x16 ahh, ahl, alh;
#pragma unroll
    for (int r = 0; r < 16; ++r) { ahh[r] = 0.f; ahl[r] = 0.f; alh[r] = 0.f; }
#pragma unroll
    for (int s = 0; s < 16; ++s) {
      const int off = ((s * 2 + hi) << 8) + (col << 3);  // shorts; 16B-aligned
      const short8 bh = *(const short8*)(bhB + off);
      const short8 bl = *(const short8*)(blB + off);
      ahh = __builtin_amdgcn_mfma_f32_32x32x16_bf16(ah[s], bh, ahh, 0, 0, 0);
      ahl = __builtin_amdgcn_mfma_f32_32x32x16_bf16(ah[s], bl, ahl, 0, 0, 0);
      alh = __builtin_amdgcn_mfma_f32_32x32x16_bf16(al[s], bh, alh, 0, 0, 0);
    }

    const int cc = chunk * 32 + col;
    const float wq = swsq[cc];
#pragma unroll
    for (int r = 0; r < 16; ++r) {
      const float sc = fmaf(2.f, ahh[r] + ahl[r] + alh[r], -wq);
      const bool gt = sc > s1[r];
      s2[r] = fmaxf(s2[r], gt ? s1[r] : sc);
      if (gt) { s1[r] = sc; i1[r] = cc; }
    }
    __syncthreads();  // staging DMA drained + compute done before buffer reuse
  }

  // cross-lane top-2 merge (masks 1..16 keep hi fixed -> same token set)
#pragma unroll
  for (int m = 1; m <= 16; m <<= 1) {
#pragma unroll
    for (int r = 0; r < 16; ++r) {
      const float os1 = __shfl_xor(s1[r], m);
      const int   oi1 = __shfl_xor(i1[r], m);
      const float os2 = __shfl_xor(s2[r], m);
      const bool take = (os1 > s1[r]) || (os1 == s1[r] && oi1 < i1[r]);
      const float loser = take ? s1[r] : os1;
      if (take) { s1[r] = os1; i1[r] = oi1; }
      s2[r] = fmaxf(fmaxf(s2[r], os2), loser);
    }
  }

  const size_t tb = (size_t)blockIdx.x * 128 + wv * 32;

  if (col == 0) {
#pragma unroll
    for (int r = 0; r < 16; ++r) {
      const int row = (r & 3) + 8 * (r >> 2) + 4 * hi;  // C/D row map (m74/m101)
      const size_t g = tb + row;
      idxInt[g] = i1[r];
      out[OFF_IDX + g] = (float)i1[r];
      atomicAdd(countsInt + i1[r], 1);
      if (s1[r] - s2[r] < FLAG_TH) {
        const int slot = atomicAdd(flagCnt, 1);
        if (slot < FLAG_CAP) flagged[slot] = (int)g;
      }
    }
  }

  // fused quantize write: half-wave (32 lanes) per token row, 8 floats/lane
  const int l32 = lane & 31;
#pragma unroll
  for (int r = 0; r < 16; ++r) {
    const int row = (r & 3) + 8 * (r >> 2) + 4 * hi;
    const size_t t = tb + row;
    const int k = i1[r];  // uniform within half-wave
    const float* wrow = wT + (size_t)k * D + l32 * 8;
    const float4 q0 = *(const float4*)(wrow);
    const float4 q1 = *(const float4*)(wrow + 4);
    float* od = out + OFF_Q + t * D + l32 * 8;  // base misaligned by 1 float
    od[0] = q0.x; od[1] = q0.y; od[2] = q0.z; od[3] = q0.w;
    od[4] = q1.x; od[5] = q1.y; od[6] = q1.z; od[7] = q1.w;
  }
}

// ---- exact fp32 rescan: private keys per (slot, chunk), no contention ----
__global__ __launch_bounds__(256) void vq_fixup(
    const float* __restrict__ x, const float* __restrict__ wT,
    const float* __restrict__ wsq, const int* __restrict__ flagCnt,
    const int* __restrict__ flagged, unsigned long long* __restrict__ keyBuf) {
  __shared__ float ws32[32 * 264];
  __shared__ float xs[D];
  __shared__ unsigned long long wred[4];
  const int tid = threadIdx.x;
  const int cc = blockIdx.x & 31, j0 = blockIdx.x >> 5;  // 32 chunks x 16 groups
#pragma unroll
  for (int r = 0; r < 32; ++r)
    ws32[r * 264 + tid] = wT[(size_t)(cc * 32 + r) * D + tid];
  int F = *flagCnt;
  if (F > FLAG_CAP) F = FLAG_CAP;
  const int ci = tid >> 3, dg = tid & 7, c = cc * 32 + ci;
  const float wq = wsq[c];

  for (int slot = j0; slot < F; slot += 16) {
    const int t = flagged[slot];
    __syncthreads();
    xs[tid] = x[(size_t)t * D + tid];
    __syncthreads();
    float dot = 0.f;
#pragma unroll
    for (int i = 0; i < 32; ++i)
      dot = fmaf(xs[dg + 8 * i], ws32[ci * 264 + dg + 8 * i], dot);
    dot += __shfl_xor(dot, 1);
    dot += __shfl_xor(dot, 2);
    dot += __shfl_xor(dot, 4);
    unsigned long long key = 0ull;
    if (dg == 0) {
      const float sc = fmaf(2.f, dot, -wq);
      unsigned u = __float_as_uint(sc);
      u = (u & 0x80000000u) ? ~u : (u | 0x80000000u);
      key = ((unsigned long long)u << 32) | (unsigned)(1023 - c);
    }
#pragma unroll
    for (int m = 8; m <= 32; m <<= 1) {
      const unsigned long long o = __shfl_xor(key, m);
      if (o > key) key = o;
    }
    if ((tid & 63) == 0) wred[tid >> 6] = key;
    __syncthreads();
    if (tid == 0) {
      unsigned long long b = wred[0];
      if (wred[1] > b) b = wred[1];
      if (wred[2] > b) b = wred[2];
      if (wred[3] > b) b = wred[3];
      keyBuf[(size_t)slot * 32 + cc] = b;
    }
  }
}

// ---- finalize flagged tokens: fix idx, counts, and quantize row ----
__global__ __launch_bounds__(256) void vq_fixfin(
    const int* __restrict__ flagCnt, const int* __restrict__ flagged,
    const unsigned long long* __restrict__ keyBuf, int* __restrict__ idxInt,
    int* __restrict__ countsInt, const float* __restrict__ wT,
    float* __restrict__ out) {
  int F = *flagCnt;
  if (F > FLAG_CAP) F = FLAG_CAP;
  const int wv = threadIdx.x >> 6, lane = threadIdx.x & 63;
  for (int slot = blockIdx.x * 4 + wv; slot < F; slot += 64) {
    const int t = flagged[slot];
    unsigned long long key = (lane < 32) ? keyBuf[(size_t)slot * 32 + lane] : 0ull;
#pragma unroll
    for (int m = 1; m <= 32; m <<= 1) {
      const unsigned long long o = __shfl_xor(key, m);
      if (o > key) key = o;
    }
    const int c = 1023 - (int)(key & 0xFFFFFFFFull);
    const int old = idxInt[t];
    if (c != old) {
      if (lane == 0) {
        idxInt[t] = c;
        out[OFF_IDX + t] = (float)c;
        atomicAdd(countsInt + old, -1);
        atomicAdd(countsInt + c, 1);
      }
      const float4 q = *(const float4*)(wT + (size_t)c * D + lane * 4);
      float* od = out + OFF_Q + (size_t)t * D + lane * 4;
      od[0] = q.x; od[1] = q.y; od[2] = q.z; od[3] = q.w;
    }
  }
}

// ---- scan: counts -> cluster-size output, bucket starts, cursors ----
__global__ __launch_bounds__(1024) void vq_scan(const int* __restrict__ countsInt,
                                                int* __restrict__ bucketStart,
                                                int* __restrict__ cursorInt,
                                                float* __restrict__ out) {
  __shared__ int sc[1024];
  const int tid = threadIdx.x;
  const int c = countsInt[tid];
  out[OFF_CS + tid] = (float)c;
  sc[tid] = c;
  __syncthreads();
  for (int off = 1; off < 1024; off <<= 1) {
    int v = 0;
    if (tid >= off) v = sc[tid - off];
    __syncthreads();
    if (tid >= off) sc[tid] += v;
    __syncthreads();
  }
  bucketStart[tid] = sc[tid] - c;  // exclusive
  cursorInt[tid] = 0;
}

__global__ __launch_bounds__(256) void vq_scatter(const int* __restrict__ idxInt,
                                                  const int* __restrict__ bucketStart,
                                                  int* __restrict__ cursorInt,
                                                  int* __restrict__ sortedTok) {
  const int t = blockIdx.x * 256 + threadIdx.x;
  const int k = idxInt[t];
  const int pos = atomicAdd(cursorInt + k, 1);
  sortedTok[bucketStart[k] + pos] = t;
}

// ---- dw + loss over sorted tokens: 16 positions per wave, flush on change ----
__global__ __launch_bounds__(256) void vq_dwloss(
    const float* __restrict__ x, const float* __restrict__ wT,
    const int* __restrict__ idxInt, const int* __restrict__ sortedTok,
    float* __restrict__ dwT, float* __restrict__ lossAcc) {
  __shared__ float sRed[4];
  const int tid = threadIdx.x, wv = tid >> 6, lane = tid & 63;
  const int g = blockIdx.x * 4 + wv;   // 4096 waves
  const int p0 = g * 16;
  const int tk = sortedTok[p0 + (lane & 15)];
  const int kk = idxInt[tk];

  int kcur = -1;
  float4 acc = {0.f, 0.f, 0.f, 0.f};
  float4 wv4 = {0.f, 0.f, 0.f, 0.f};
  float lp = 0.f;
#pragma unroll
  for (int i = 0; i < 16; ++i) {
    const int t = __shfl(tk, i);
    const int k = __shfl(kk, i);
    if (k != kcur) {
      if (kcur >= 0) {
        float* dr = dwT + (size_t)kcur * D + lane * 4;
        atomicAdd(dr + 0, acc.x); atomicAdd(dr + 1, acc.y);
        atomicAdd(dr + 2, acc.z); atomicAdd(dr + 3, acc.w);
      }
      acc = {0.f, 0.f, 0.f, 0.f};
      wv4 = *(const float4*)(wT + (size_t)k * D + lane * 4);
      kcur = k;
    }
    const float4 xv = *(const float4*)(x + (size_t)t * D + lane * 4);
    acc.x += xv.x; acc.y += xv.y; acc.z += xv.z; acc.w += xv.w;
    const float dx = wv4.x - xv.x, dy = wv4.y - xv.y;
    const float dz = wv4.z - xv.z, dw = wv4.w - xv.w;
    lp = fmaf(dx, dx, lp); lp = fmaf(dy, dy, lp);
    lp = fmaf(dz, dz, lp); lp = fmaf(dw, dw, lp);
  }
  {
    float* dr = dwT + (size_t)kcur * D + lane * 4;
    atomicAdd(dr + 0, acc.x); atomicAdd(dr + 1, acc.y);
    atomicAdd(dr + 2, acc.z); atomicAdd(dr + 3, acc.w);
  }
#pragma unroll
  for (int m = 1; m < 64; m <<= 1) lp += __shfl_xor(lp, m);
  if (lane == 0) sRed[wv] = lp;
  __syncthreads();
  if (tid == 0) atomicAdd(lossAcc, sRed[0] + sRed[1] + sRed[2] + sRed[3]);
}

__global__ __launch_bounds__(256) void transpose_dw(const float* __restrict__ dwT,
                                                    float* __restrict__ out) {
  __shared__ float tile[32][33];
  const int d0 = blockIdx.x * 32, k0 = blockIdx.y * 32;
  const int tx = threadIdx.x, ty = threadIdx.y;  // 32x8
#pragma unroll
  for (int j = 0; j < 4; ++j) {
    const int r = ty + j * 8;
    tile[r][tx] = dwT[(size_t)(k0 + r) * D + d0 + tx];
  }
  __syncthreads();
#pragma unroll
  for (int j = 0; j < 4; ++j) {
    const int r = ty + j * 8;
    out[OFF_DW + (size_t)(d0 + r) * K + k0 + tx] = tile[tx][r];
  }
}

__global__ __launch_bounds__(1024) void finalize_kernel(const float* __restrict__ lossAcc,
                                                        float* __restrict__ out) {
  __shared__ float red[16];
  const int tid = threadIdx.x;
  const float c = out[OFF_CS + tid];
  const float avg = c * (1.0f / (float)NTOK);
  float term = avg * logf(avg + 1e-10f);
#pragma unroll
  for (int m = 1; m < 64; m <<= 1) term += __shfl_xor(term, m);
  const int wave = tid >> 6, lane = tid & 63;
  if (lane == 0) red[wave] = term;
  __syncthreads();
  if (tid == 0) {
    float s = 0.f;
#pragma unroll
    for (int i = 0; i < 16; ++i) s += red[i];
    out[OFF_P] = expf(-s);
    out[0] = lossAcc[0] * (1.0f / ((float)NTOK * (float)D));
  }
}

extern "C" void kernel_launch(void* const* d_in, const int* in_sizes, int n_in,
                              void* d_out, int out_size, void* d_ws, size_t ws_size,
                              hipStream_t stream) {
  const float* x = (const float*)d_in[0];
  const float* w = (const float*)d_in[1];
  float* out = (float*)d_out;
  char* wsb = (char*)d_ws;

  // ws layout (bytes)
  float* lossAcc     = (float*)(wsb + 0);
  int*   flagCnt     = (int*)(wsb + 4);
  int*   countsInt   = (int*)(wsb + 4096);
  int*   bucketStart = (int*)(wsb + 8192);
  int*   cursorInt   = (int*)(wsb + 12288);
  float* wsq         = (float*)(wsb + 16384);
  int*   idxInt      = (int*)(wsb + 20480);                        // 256 KB
  int*   sortedTok   = (int*)(wsb + 282624);                       // 256 KB
  int*   flagged     = (int*)(wsb + 544768);                       // 32 KB
  unsigned long long* keyBuf = (unsigned long long*)(wsb + 577536);  // 2 MB
  float* wT          = (float*)(wsb + 2674688);                    // 1 MB
  unsigned short* wBG = (unsigned short*)(wsb + 3723264);          // 1 MB
  float* dwT         = (float*)(wsb + 4771840);                    // 1 MB

  // zero accumulators (d_ws is 0xAA-poisoned before every timed call)
  hipMemsetAsync(wsb, 0, 20480, stream);
  hipMemsetAsync(dwT, 0, sizeof(float) * (size_t)K * D, stream);

  prep_w<<<dim3(K / 32, D / 32), dim3(32, 8), 0, stream>>>(w, wT, wBG);
  wsq_kernel<<<dim3(K / 4), dim3(256), 0, stream>>>(wT, wsq);
  vq_score<<<dim3(NTOK / 128), dim3(256), 0, stream>>>(
      x, wBG, wsq, wT, out, idxInt, countsInt, flagCnt, flagged);
  vq_fixup<<<dim3(512), dim3(256), 0, stream>>>(x, wT, wsq, flagCnt, flagged, keyBuf);
  vq_fixfin<<<dim3(16), dim3(256), 0, stream>>>(flagCnt, flagged, keyBuf, idxInt,
                                                countsInt, wT, out);
  vq_scan<<<dim3(1), dim3(1024), 0, stream>>>(countsInt, bucketStart, cursorInt, out);
  vq_scatter<<<dim3(NTOK / 256), dim3(256), 0, stream>>>(idxInt, bucketStart,
                                                         cursorInt, sortedTok);
  vq_dwloss<<<dim3(1024), dim3(256), 0, stream>>>(x, wT, idxInt, sortedTok,
                                                  dwT, lossAcc);
  transpose_dw<<<dim3(D / 32, K / 32), dim3(32, 8), 0, stream>>>(dwT, out);
  finalize_kernel<<<dim3(1), dim3(1024), 0, stream>>>(lossAcc, out);
}